// Round 2
// baseline (67.058 us; speedup 1.0000x reference)
//
#include <hip/hip_runtime.h>

// DilateAttention: q,k,v [B=16, d=32, H=128, W=128] fp32, kernel=3, dilation=2, pad=2.
// Per-pixel 1x9 attention over dilated 3x3 window; OOB taps are zero-padded
// (score 0, value 0) and participate in the softmax denominator.
//
// Decomposition: block = one (b,h) row, 256 threads = 4 waves.
// lane = dg*16 + wtl (dg in [0,4) handles 8 d's; wt = waveid*16+wtl in [0,64)
// handles 2 consecutive w pixels). Partial QK scores reduced over dg via
// shfl_xor(16)+shfl_xor(32) -- register-only, no LDS, no barrier.
// All global accesses are float2 (8B, 8B-aligned).

#define BB 16
#define HD 32
#define HH 128
#define WW 128
#define PLANE (HH * WW)

__global__ __launch_bounds__(256) void dilate_attn_kernel(
    const float* __restrict__ q,
    const float* __restrict__ k,
    const float* __restrict__ v,
    float* __restrict__ out)
{
    const int tid    = threadIdx.x;
    const int lane   = tid & 63;
    const int waveid = tid >> 6;
    const int dg     = lane >> 4;          // 0..3 -> d in [dg*8, dg*8+8)
    const int wtl    = lane & 15;          // 0..15
    const int wt     = waveid * 16 + wtl;  // 0..63
    const int w2     = wt * 2;             // 0,2,..,126 (2 pixels: w2, w2+1)

    const int h = blockIdx.x & (HH - 1);
    const int b = blockIdx.x >> 7;

    const int d0 = dg * 8;
    const size_t chanBase = ((size_t)b * HD + d0) * PLANE;
    const int pix = h * WW + w2;

    // Row taps: h-2, h, h+2 (uniform validity across the block).
    const bool row_ok[3] = { h >= 2, true, h < HH - 2 };
    const int  row_off[3] = { -2 * WW, 0, 2 * WW };
    // Column edge guards: lo2 covers cols w2-2,w2-1; hi2 covers w2+2,w2+3.
    const bool lo_ok = (wt > 0);
    const bool hi_ok = (w2 + 2 < WW);

    // ---- Pass 1: partial scores over this dg's 8 d's ----
    float s[2][9];
    #pragma unroll
    for (int p = 0; p < 2; ++p)
        #pragma unroll
        for (int n = 0; n < 9; ++n) s[p][n] = 0.f;

    const float* qbase = q + chanBase + pix;
    const float* kbase = k + chanBase + pix;

    #pragma unroll 4
    for (int dd = 0; dd < 8; ++dd) {
        const float2 q2 = *(const float2*)(qbase + dd * PLANE);
        const float* kp = kbase + dd * PLANE;
        #pragma unroll
        for (int i = 0; i < 3; ++i) {
            if (!row_ok[i]) continue;  // wave-uniform branch
            const float* kr = kp + row_off[i];
            float2 lo = lo_ok ? *(const float2*)(kr - 2) : make_float2(0.f, 0.f);
            float2 ce = *(const float2*)(kr);
            float2 hi = hi_ok ? *(const float2*)(kr + 2) : make_float2(0.f, 0.f);
            float r[6] = { lo.x, lo.y, ce.x, ce.y, hi.x, hi.y };
            #pragma unroll
            for (int j = 0; j < 3; ++j) {
                s[0][i * 3 + j] = fmaf(q2.x, r[0 + 2 * j], s[0][i * 3 + j]);
                s[1][i * 3 + j] = fmaf(q2.y, r[1 + 2 * j], s[1][i * 3 + j]);
            }
        }
    }

    // ---- Reduce partial scores over the 4 d-groups (lanes xor 16, 32) ----
    #pragma unroll
    for (int p = 0; p < 2; ++p) {
        #pragma unroll
        for (int n = 0; n < 9; ++n) {
            float x = s[p][n];
            x += __shfl_xor(x, 16);
            x += __shfl_xor(x, 32);
            s[p][n] = x;
        }
    }

    // ---- Softmax over 9 taps (duplicated across dg; cheap) ----
    const float scale = 0.17677669529663687f;  // 32^-0.5
    #pragma unroll
    for (int p = 0; p < 2; ++p) {
        float m = -3.4e38f;
        #pragma unroll
        for (int n = 0; n < 9; ++n) { s[p][n] *= scale; m = fmaxf(m, s[p][n]); }
        float sum = 0.f;
        #pragma unroll
        for (int n = 0; n < 9; ++n) { s[p][n] = __expf(s[p][n] - m); sum += s[p][n]; }
        const float inv = 1.f / sum;
        #pragma unroll
        for (int n = 0; n < 9; ++n) s[p][n] *= inv;
    }

    // ---- Pass 2: out[d] = sum_n attn[n] * v_tap[n], for this dg's 8 d's ----
    const float* vbase = v + chanBase + pix;
    float* obase = out + chanBase + pix;

    #pragma unroll 4
    for (int dd = 0; dd < 8; ++dd) {
        const float* vp = vbase + dd * PLANE;
        float acc0 = 0.f, acc1 = 0.f;
        #pragma unroll
        for (int i = 0; i < 3; ++i) {
            if (!row_ok[i]) continue;
            const float* vr = vp + row_off[i];
            float2 lo = lo_ok ? *(const float2*)(vr - 2) : make_float2(0.f, 0.f);
            float2 ce = *(const float2*)(vr);
            float2 hi = hi_ok ? *(const float2*)(vr + 2) : make_float2(0.f, 0.f);
            float r[6] = { lo.x, lo.y, ce.x, ce.y, hi.x, hi.y };
            #pragma unroll
            for (int j = 0; j < 3; ++j) {
                acc0 = fmaf(s[0][i * 3 + j], r[0 + 2 * j], acc0);
                acc1 = fmaf(s[1][i * 3 + j], r[1 + 2 * j], acc1);
            }
        }
        *(float2*)(obase + dd * PLANE) = make_float2(acc0, acc1);
    }
}

extern "C" void kernel_launch(void* const* d_in, const int* in_sizes, int n_in,
                              void* d_out, int out_size, void* d_ws, size_t ws_size,
                              hipStream_t stream) {
    const float* q = (const float*)d_in[0];
    const float* k = (const float*)d_in[1];
    const float* v = (const float*)d_in[2];
    float* out = (float*)d_out;

    dim3 grid(BB * HH);   // one block per (b, h) row
    dim3 block(256);      // 4 waves: 64 wt-slots x 4 d-groups
    dilate_attn_kernel<<<grid, block, 0, stream>>>(q, k, v, out);
}